// Round 1
// baseline (37.774 us; speedup 1.0000x reference)
//
#include <hip/hip_runtime.h>
#include <math.h>

// CorticalMicrocircuit: dy = f(params, t, y, drive). Elementwise over B circuits.
// out rows 0..5 = y rows 6..11; out rows 6..11 = drive + M·F(y[0..5]) - damping.
// Memory-bound: 201 MB total traffic -> ~32 us floor at 6.3 TB/s.

__global__ __launch_bounds__(256) void cc_kernel(
    const float* __restrict__ params,
    const float* __restrict__ blo,
    const float* __restrict__ bhi,
    const float* __restrict__ tptr,
    const float* __restrict__ y,
    const float* __restrict__ drive,
    float* __restrict__ out,
    int n, int tsteps)
{
    // sc layout: [0..5]=r, [6..11]=r*v0, [12..17]=2*e0, [18..23]=2*g,
    //            [24..29]=g^2, [30..35]=drive row, [36..71]=M[6][6]
    __shared__ float sc[72];
    __shared__ float p[59];

    const int tid = threadIdx.x;
    if (tid < 59) {
        float v = params[tid];
        p[tid] = fminf(fmaxf(v, blo[tid]), bhi[tid]);
    }
    __syncthreads();

    if (tid == 0) {
        float A_p23_p23=p[0], A_p23_p5=p[1], A_p23_st=p[2], A_p23_PV=p[3],
              A_p23_SST=p[4], A_p23_VIP=p[5], a_p23=p[6], e0_p23=p[7],
              v0_p23=p[8], r_p23=p[9];
        float A_p5_p5=p[10], A_p5_st=p[11], A_p5_PV=p[12], A_p5_SST=p[13],
              a_p5=p[14], e0_p5=p[15], v0_p5=p[16], r_p5=p[17];
        float A_st_p23=p[18], A_st_p5=p[19], A_st_PV=p[21],
              A_st_SST=p[22], a_st=p[23], e0_st=p[24], v0_st=p[25], r_st=p[26];
        float B_PV_p23=p[27], B_PV_p5=p[28], B_PV_st=p[29], B_PV_PV=p[30],
              B_PV_SST=p[31], B_PV_VIP=p[32], b_PV=p[33], e0_PV=p[34],
              v0_PV=p[35], r_PV=p[36];
        float B_SST_p23=p[37], B_SST_p5=p[38], B_SST_PV=p[39], B_SST_SST=p[40],
              B_SST_VIP=p[41], b_SST=p[42], e0_SST=p[43], v0_SST=p[44], r_SST=p[45];
        float B_VIP_PV=p[46], B_VIP_SST=p[47], B_VIP_VIP=p[48], b_VIP=p[49],
              e0_VIP=p[50], v0_VIP=p[51], r_VIP=p[52];
        float N_p23=p[53], N_p5=p[54], N_st=p[55], N_PV=p[56], N_SST=p[57], N_VIP=p[58];

        const float rr[6] = {r_p23, r_p5, r_st, r_PV, r_SST, r_VIP};
        const float vv[6] = {v0_p23, v0_p5, v0_st, v0_PV, v0_SST, v0_VIP};
        const float ee[6] = {e0_p23, e0_p5, e0_st, e0_PV, e0_SST, e0_VIP};
        const float gg[6] = {a_p23, a_p5, a_st, b_PV, b_SST, b_VIP};
        for (int k = 0; k < 6; ++k) {
            sc[k]      = rr[k];
            sc[6 + k]  = rr[k] * vv[k];
            sc[12 + k] = 2.0f * ee[k];
            sc[18 + k] = 2.0f * gg[k];
            sc[24 + k] = gg[k] * gg[k];
        }

        // drive row
        float t = *tptr;
        float fi = fminf(fmaxf(t / 0.002f, 0.0f), (float)(tsteps - 1));
        int ti = (int)fi;   // truncation matches astype(int32)
        for (int k = 0; k < 6; ++k) sc[30 + k] = drive[(size_t)ti * 6 + k];

        // coupling matrix M[i][j]: contribution of F_j (pops P23,P5,St,PV,SST,VIP)
        // to output row 6+i.
        float M[36];
        for (int i = 0; i < 36; ++i) M[i] = 0.0f;
        M[0*6+0] =  A_p23_p23 * a_p23;
        M[0*6+2] =  A_st_p23  * a_st  * (N_st  / N_p23);
        M[0*6+3] = -B_PV_p23  * b_PV  * (N_PV  / N_p23);
        M[0*6+4] = -B_SST_p23 * b_SST * (N_SST / N_p23);

        M[1*6+0] =  A_p23_p5  * a_p23 * (N_p23 / N_p5);
        M[1*6+1] =  A_p5_p5   * a_p5;
        M[1*6+2] =  A_st_p5   * a_st  * (N_st  / N_p5);
        M[1*6+3] = -B_PV_p5   * b_PV  * (N_PV  / N_p5);
        M[1*6+4] = -B_SST_p5  * b_SST * (N_SST / N_p5);

        M[2*6+0] =  A_p23_st  * a_p23 * (N_p23 / N_st);
        M[2*6+1] =  A_p5_st   * a_p5  * (N_p5  / N_st);
        M[2*6+3] = -B_PV_st   * b_PV  * (N_PV  / N_st);

        M[3*6+0] =  A_p23_PV  * a_p23 * (N_p23 / N_PV);
        M[3*6+1] =  A_p5_PV   * a_p5  * (N_p5  / N_PV);
        M[3*6+2] =  A_st_PV   * a_st  * (N_st  / N_PV);
        M[3*6+3] = -B_PV_PV   * b_PV;
        M[3*6+4] = -B_SST_PV  * b_SST * (N_SST / N_PV);
        M[3*6+5] = -B_VIP_PV  * b_VIP * (N_VIP / N_PV);

        M[4*6+0] =  A_p23_SST * a_p23 * (N_p23 / N_SST);
        M[4*6+1] =  A_p5_SST  * a_p5  * (N_p5  / N_SST);
        M[4*6+2] =  A_st_SST  * a_st  * (N_st  / N_SST);
        M[4*6+3] = -B_PV_SST  * b_PV  * (N_PV  / N_SST);
        M[4*6+4] = -B_SST_SST * b_SST;
        M[4*6+5] = -B_VIP_SST * b_VIP * (N_VIP / N_SST);

        M[5*6+0] =  A_p23_VIP * a_p23 * (N_p23 / N_VIP);
        M[5*6+3] = -B_PV_VIP  * b_PV  * (N_PV  / N_VIP);
        M[5*6+4] = -B_SST_VIP * b_SST * (N_SST / N_VIP);
        M[5*6+5] = -B_VIP_VIP * b_VIP;

        for (int i = 0; i < 36; ++i) sc[36 + i] = M[i];
    }
    __syncthreads();

    const size_t i4 = ((size_t)blockIdx.x * blockDim.x + threadIdx.x) * 4;
    if (i4 + 3 >= (size_t)n && i4 >= (size_t)n) return;

    // Load all 12 state rows (float4 per row)
    float4 v[12];
#pragma unroll
    for (int r = 0; r < 12; ++r)
        v[r] = *(const float4*)(y + (size_t)r * n + i4);

    // out rows 0..5 = y rows 6..11 (the first-order derivatives pass through)
#pragma unroll
    for (int r = 0; r < 6; ++r)
        *(float4*)(out + (size_t)r * n + i4) = v[6 + r];

    // Sigmoid firing rates F[pop][elem] = 2*e0 / (1 + exp(r*v0 - r*v))
    float F[6][4];
#pragma unroll
    for (int k = 0; k < 6; ++k) {
        const float rk  = sc[k];
        const float rv0 = sc[6 + k];
        const float e2  = sc[12 + k];
        const float* vk = (const float*)&v[k];
#pragma unroll
        for (int j = 0; j < 4; ++j)
            F[k][j] = e2 / (1.0f + __expf(rv0 - rk * vk[j]));
    }

    // out rows 6..11
#pragma unroll
    for (int i = 0; i < 6; ++i) {
        const float dr  = sc[30 + i];
        const float tg  = sc[18 + i];
        const float gsq = sc[24 + i];
        const float* vi = (const float*)&v[i];
        const float* di = (const float*)&v[6 + i];
        float4 o;
        float* op = (float*)&o;
#pragma unroll
        for (int j = 0; j < 4; ++j) {
            float acc = dr;
#pragma unroll
            for (int k = 0; k < 6; ++k)
                acc = fmaf(sc[36 + i * 6 + k], F[k][j], acc);
            acc = fmaf(-tg, di[j], acc);
            acc = fmaf(-gsq, vi[j], acc);
            op[j] = acc;
        }
        *(float4*)(out + (size_t)(6 + i) * n + i4) = o;
    }
}

extern "C" void kernel_launch(void* const* d_in, const int* in_sizes, int n_in,
                              void* d_out, int out_size, void* d_ws, size_t ws_size,
                              hipStream_t stream) {
    const float* params = (const float*)d_in[0];
    const float* blo    = (const float*)d_in[1];
    const float* bhi    = (const float*)d_in[2];
    const float* tptr   = (const float*)d_in[3];
    const float* y      = (const float*)d_in[4];
    const float* drive  = (const float*)d_in[5];
    float* out = (float*)d_out;

    const int n      = in_sizes[4] / 12;   // B
    const int tsteps = in_sizes[5] / 6;    // T

    const int threads = 256;
    const int elems_per_block = threads * 4;
    const int blocks = (n + elems_per_block - 1) / elems_per_block;  // 2048 for B=2^21

    cc_kernel<<<blocks, threads, 0, stream>>>(params, blo, bhi, tptr, y, drive,
                                              out, n, tsteps);
}